// Round 1
// baseline (374.882 us; speedup 1.0000x reference)
//
#include <hip/hip_runtime.h>

// ---------------------------------------------------------------------------
// BiasedAttention fused pipeline (MI355X / gfx950)
//   x[8,1024,1024] f32 -> LN -> bf16
//   qkv = xn @ Wqkv (bf16 MFMA, fp32 acc)  [8192, 3072] bf16
//   flash attention w/ additive bias (fp32 softmax)  -> [8192,1024] bf16
//   out = attn_out @ Wout -> f32 d_out
// Workspace layout (bytes):
//   xn      bf16  8192*1024*2  = 16777216   @ 0
//   wqkv_t  bf16  3072*1024*2  =  6291456   @ 16777216
//   wout_t  bf16  1024*1024*2  =  2097152   @ 23068672
//   qkv     bf16  8192*3072*2  = 50331648   @ 25165824
//   aout    bf16  8192*1024*2  = 16777216   @ 75497472
//   total 92274688 B
// ---------------------------------------------------------------------------

#define DIM    1024
#define HEADS  16
#define DHEAD  64
#define INNER  1024
#define SEQ    1024
#define BATCH  8
#define QKV3   3072

typedef __bf16 bf16x8 __attribute__((ext_vector_type(8)));
typedef float f32x4 __attribute__((ext_vector_type(4)));
typedef unsigned short u16x8 __attribute__((ext_vector_type(8)));
typedef unsigned short u16x4 __attribute__((ext_vector_type(4)));

typedef __attribute__((address_space(1))) const unsigned int as1_uint;
typedef __attribute__((address_space(3))) unsigned int as3_uint;

static __device__ inline unsigned short f2bf(float f) {
  unsigned int u = __float_as_uint(f);
  u = (u + 0x7FFFu + ((u >> 16) & 1u)) >> 16;  // RNE
  return (unsigned short)u;
}

// ---------------------------------------------------------------------------
// 1. LayerNorm fp32 -> bf16
// ---------------------------------------------------------------------------
__global__ __launch_bounds__(256) void ln_bf16_kernel(
    const float* __restrict__ x, const float* __restrict__ gamma,
    const float* __restrict__ beta, unsigned short* __restrict__ xn) {
  int row = blockIdx.x;
  int tid = threadIdx.x;
  const float4* xr = reinterpret_cast<const float4*>(x + (size_t)row * DIM);
  float4 v = xr[tid];
  float s = v.x + v.y + v.z + v.w;
  float s2 = v.x * v.x + v.y * v.y + v.z * v.z + v.w * v.w;
#pragma unroll
  for (int m = 32; m; m >>= 1) {
    s += __shfl_xor(s, m, 64);
    s2 += __shfl_xor(s2, m, 64);
  }
  __shared__ float red[2][4];
  int wid = tid >> 6, lane = tid & 63;
  if (lane == 0) { red[0][wid] = s; red[1][wid] = s2; }
  __syncthreads();
  s = red[0][0] + red[0][1] + red[0][2] + red[0][3];
  s2 = red[1][0] + red[1][1] + red[1][2] + red[1][3];
  float mu = s * (1.0f / DIM);
  float var = s2 * (1.0f / DIM) - mu * mu;
  float rstd = rsqrtf(var + 1e-5f);
  float4 g = reinterpret_cast<const float4*>(gamma)[tid];
  float4 b = reinterpret_cast<const float4*>(beta)[tid];
  u16x4 o;
  o[0] = f2bf((v.x - mu) * rstd * g.x + b.x);
  o[1] = f2bf((v.y - mu) * rstd * g.y + b.y);
  o[2] = f2bf((v.z - mu) * rstd * g.z + b.z);
  o[3] = f2bf((v.w - mu) * rstd * g.w + b.w);
  *reinterpret_cast<u16x4*>(xn + (size_t)row * DIM + tid * 4) = o;
}

// ---------------------------------------------------------------------------
// 2. Transpose + fp32->bf16:  W[R][C] -> Wt[C][R]
// ---------------------------------------------------------------------------
__global__ __launch_bounds__(256) void transpose_cvt(
    const float* __restrict__ W, unsigned short* __restrict__ Wt, int R, int C) {
  __shared__ float tb[32][33];
  int c0 = blockIdx.x * 32, r0 = blockIdx.y * 32;
  int tx = threadIdx.x, ty = threadIdx.y;  // (32, 8)
#pragma unroll
  for (int i = 0; i < 4; ++i)
    tb[ty + i * 8][tx] = W[(size_t)(r0 + ty + i * 8) * C + c0 + tx];
  __syncthreads();
#pragma unroll
  for (int i = 0; i < 4; ++i)
    Wt[(size_t)(c0 + ty + i * 8) * R + r0 + tx] = f2bf(tb[tx][ty + i * 8]);
}

// ---------------------------------------------------------------------------
// 3. GEMM  C[M,N] = A[M,K] @ Bt[N,K]^T   (bf16 in, fp32 acc)
//    m97 structure: 128x128 tile, BK=64, 4 waves (2x2), 16x16x32 MFMA,
//    global_load_lds width-16 staging, linear LDS.
// ---------------------------------------------------------------------------
template <bool F32OUT>
__global__ __launch_bounds__(256) void gemm_bt(
    const unsigned short* __restrict__ A, const unsigned short* __restrict__ Bt,
    void* __restrict__ Cout, int M, int N, int K) {
  __shared__ unsigned short As[128 * 64];
  __shared__ unsigned short Bs[128 * 64];
  int nb = N >> 7;
  int bm = blockIdx.x / nb, bn = blockIdx.x % nb;
  int tid = threadIdx.x, wid = tid >> 6, lane = tid & 63;
  int wr = wid >> 1, wc = wid & 1;
  int lg = lane >> 4, lr = lane & 15;
  f32x4 acc[4][4] = {};
  const unsigned short* Ablk = A + (size_t)(bm * 128) * K;
  const unsigned short* Bblk = Bt + (size_t)(bn * 128) * K;
  int srow = wid * 32 + (lane >> 3);  // staging row (+t*8)
  int scol = (lane & 7) * 8;          // staging col (8 bf16 = 16B)
  for (int kt = 0; kt < K; kt += 64) {
#pragma unroll
    for (int t = 0; t < 4; ++t) {
      int r = srow + t * 8;
      __builtin_amdgcn_global_load_lds(
          (as1_uint*)(Ablk + (size_t)r * K + kt + scol),
          (as3_uint*)(&As[(wid * 32 + t * 8) * 64]), 16, 0, 0);
      __builtin_amdgcn_global_load_lds(
          (as1_uint*)(Bblk + (size_t)r * K + kt + scol),
          (as3_uint*)(&Bs[(wid * 32 + t * 8) * 64]), 16, 0, 0);
    }
    __syncthreads();
#pragma unroll
    for (int kk = 0; kk < 2; ++kk) {
      bf16x8 af[4], bfr[4];
#pragma unroll
      for (int mi = 0; mi < 4; ++mi)
        af[mi] = *reinterpret_cast<const bf16x8*>(
            &As[(wr * 64 + mi * 16 + lr) * 64 + kk * 32 + lg * 8]);
#pragma unroll
      for (int ni = 0; ni < 4; ++ni)
        bfr[ni] = *reinterpret_cast<const bf16x8*>(
            &Bs[(wc * 64 + ni * 16 + lr) * 64 + kk * 32 + lg * 8]);
#pragma unroll
      for (int mi = 0; mi < 4; ++mi)
#pragma unroll
        for (int ni = 0; ni < 4; ++ni)
          acc[mi][ni] = __builtin_amdgcn_mfma_f32_16x16x32_bf16(
              af[mi], bfr[ni], acc[mi][ni], 0, 0, 0);
    }
    __syncthreads();
  }
#pragma unroll
  for (int mi = 0; mi < 4; ++mi) {
    int row = bm * 128 + wr * 64 + mi * 16 + lg * 4;
#pragma unroll
    for (int ni = 0; ni < 4; ++ni) {
      int col = bn * 128 + wc * 64 + ni * 16 + lr;
#pragma unroll
      for (int j = 0; j < 4; ++j) {
        if (F32OUT)
          ((float*)Cout)[(size_t)(row + j) * N + col] = acc[mi][ni][j];
        else
          ((unsigned short*)Cout)[(size_t)(row + j) * N + col] = f2bf(acc[mi][ni][j]);
      }
    }
  }
}

// ---------------------------------------------------------------------------
// 4. Flash attention with additive bias.
//    Block = (b, h, 128 q rows). 4 waves x 32 q rows. KV tile = 64.
//    K LDS row-major padded [64][72]; V LDS transposed [d=64][72] so the PV
//    B-operand reads are K-contiguous; P per-wave [32][72].
// ---------------------------------------------------------------------------
__global__ __launch_bounds__(256) void attn_kernel(
    const unsigned short* __restrict__ qkv, const float* __restrict__ bias,
    unsigned short* __restrict__ aout) {
  int id = blockIdx.x;           // id = b + 8*(qt + 8*h)
  int b = id & 7, qt = (id >> 3) & 7, h = id >> 6;
  int tid = threadIdx.x, wid = tid >> 6, lane = tid & 63;
  int lg = lane >> 4, lr = lane & 15;

  __shared__ unsigned short Ks[64 * 72];
  __shared__ unsigned short Vt[64 * 72];
  __shared__ unsigned short Ps[4][32 * 72];

  const unsigned short* qbase = qkv + (size_t)(b * SEQ) * QKV3;
  const float* biash = bias + (size_t)h * SEQ * SEQ;

  // Q fragments in registers: 32 q rows x 64 d per wave
  bf16x8 qf[2][2];
  int q0 = qt * 128 + wid * 32;
#pragma unroll
  for (int mi = 0; mi < 2; ++mi)
#pragma unroll
    for (int kk = 0; kk < 2; ++kk)
      qf[mi][kk] = *reinterpret_cast<const bf16x8*>(
          qbase + (size_t)(q0 + mi * 16 + lr) * QKV3 + h * 64 + kk * 32 + lg * 8);

  f32x4 oacc[2][4] = {};
  float mrun[2][4], lrun[2][4];
#pragma unroll
  for (int mi = 0; mi < 2; ++mi)
#pragma unroll
    for (int j = 0; j < 4; ++j) { mrun[mi][j] = -1e30f; lrun[mi][j] = 0.f; }

  for (int t = 0; t < 16; ++t) {
    // ---- stage K (row-major, padded) and V (transposed) ----
#pragma unroll
    for (int it = 0; it < 2; ++it) {
      int e = tid + it * 256;  // 0..511
      int kr = e >> 3, kc = (e & 7) * 8;
      *reinterpret_cast<u16x8*>(&Ks[kr * 72 + kc]) =
          *reinterpret_cast<const u16x8*>(
              qbase + (size_t)(t * 64 + kr) * QKV3 + INNER + h * 64 + kc);
      int vr = e & 63, vc = (e >> 6) * 8;
      u16x8 vv = *reinterpret_cast<const u16x8*>(
          qbase + (size_t)(t * 64 + vr) * QKV3 + 2 * INNER + h * 64 + vc);
#pragma unroll
      for (int i = 0; i < 8; ++i) Vt[(vc + i) * 72 + vr] = vv[i];
    }
    __syncthreads();

    // ---- S = Q @ K^T ----
    f32x4 sacc[2][4] = {};
#pragma unroll
    for (int kk = 0; kk < 2; ++kk) {
      bf16x8 bk[4];
#pragma unroll
      for (int ni = 0; ni < 4; ++ni)
        bk[ni] = *reinterpret_cast<const bf16x8*>(
            &Ks[(ni * 16 + lr) * 72 + kk * 32 + lg * 8]);
#pragma unroll
      for (int mi = 0; mi < 2; ++mi)
#pragma unroll
        for (int ni = 0; ni < 4; ++ni)
          sacc[mi][ni] = __builtin_amdgcn_mfma_f32_16x16x32_bf16(
              qf[mi][kk], bk[ni], sacc[mi][ni], 0, 0, 0);
    }

    // ---- scale + bias + online softmax (row = 16-lane group) ----
    float p[2][4][4];
    float alpha[2][4];
#pragma unroll
    for (int mi = 0; mi < 2; ++mi) {
#pragma unroll
      for (int j = 0; j < 4; ++j) {
        int qrow = q0 + mi * 16 + lg * 4 + j;
        float sv[4], rmax = -1e30f;
#pragma unroll
        for (int ni = 0; ni < 4; ++ni) {
          int kvcol = t * 64 + ni * 16 + lr;
          float xv = sacc[mi][ni][j] * 0.125f + biash[(size_t)qrow * SEQ + kvcol];
          sv[ni] = xv;
          rmax = fmaxf(rmax, xv);
        }
#pragma unroll
        for (int m = 1; m < 16; m <<= 1) rmax = fmaxf(rmax, __shfl_xor(rmax, m, 64));
        float mnew = fmaxf(mrun[mi][j], rmax);
        float a = __expf(mrun[mi][j] - mnew);
        mrun[mi][j] = mnew;
        alpha[mi][j] = a;
        float ls = 0.f;
#pragma unroll
        for (int ni = 0; ni < 4; ++ni) {
          float e = __expf(sv[ni] - mnew);
          p[mi][ni][j] = e;
          ls += e;
        }
#pragma unroll
        for (int m = 1; m < 16; m <<= 1) ls += __shfl_xor(ls, m, 64);
        lrun[mi][j] = lrun[mi][j] * a + ls;
      }
    }

    // ---- rescale O, write P to per-wave LDS ----
#pragma unroll
    for (int mi = 0; mi < 2; ++mi)
#pragma unroll
      for (int ni = 0; ni < 4; ++ni)
#pragma unroll
        for (int j = 0; j < 4; ++j) {
          oacc[mi][ni][j] *= alpha[mi][j];
          Ps[wid][(mi * 16 + lg * 4 + j) * 72 + ni * 16 + lr] = f2bf(p[mi][ni][j]);
        }

    // P writes -> P reads is a same-wave cross-lane LDS dependency:
    // hw wait + compiler ordering fence.
    asm volatile("s_waitcnt lgkmcnt(0)" ::: "memory");

    // ---- O += P @ V ----
#pragma unroll
    for (int kk = 0; kk < 2; ++kk) {
      bf16x8 pa[2], vb[4];
#pragma unroll
      for (int mi = 0; mi < 2; ++mi)
        pa[mi] = *reinterpret_cast<const bf16x8*>(
            &Ps[wid][(mi * 16 + lr) * 72 + kk * 32 + lg * 8]);
#pragma unroll
      for (int ni = 0; ni < 4; ++ni)
        vb[ni] = *reinterpret_cast<const bf16x8*>(
            &Vt[(ni * 16 + lr) * 72 + kk * 32 + lg * 8]);
#pragma unroll
      for (int mi = 0; mi < 2; ++mi)
#pragma unroll
        for (int ni = 0; ni < 4; ++ni)
          oacc[mi][ni] = __builtin_amdgcn_mfma_f32_16x16x32_bf16(
              pa[mi], vb[ni], oacc[mi][ni], 0, 0, 0);
    }
    __syncthreads();
  }

  // ---- epilogue: O / l -> aout bf16 ----
#pragma unroll
  for (int mi = 0; mi < 2; ++mi)
#pragma unroll
    for (int j = 0; j < 4; ++j) {
      float inv = 1.0f / lrun[mi][j];
      int n = q0 + mi * 16 + lg * 4 + j;
#pragma unroll
      for (int ni = 0; ni < 4; ++ni) {
        int d = ni * 16 + lr;
        aout[(size_t)(b * SEQ + n) * INNER + h * 64 + d] = f2bf(oacc[mi][ni][j] * inv);
      }
    }
}

// ---------------------------------------------------------------------------
extern "C" void kernel_launch(void* const* d_in, const int* in_sizes, int n_in,
                              void* d_out, int out_size, void* d_ws, size_t ws_size,
                              hipStream_t stream) {
  const float* x = (const float*)d_in[0];
  const float* gamma = (const float*)d_in[1];
  const float* beta = (const float*)d_in[2];
  const float* w_qkv = (const float*)d_in[3];
  const float* w_out = (const float*)d_in[4];
  const float* bias = (const float*)d_in[5];

  char* ws = (char*)d_ws;
  unsigned short* xn = (unsigned short*)(ws);
  unsigned short* wqkv_t = (unsigned short*)(ws + 16777216);
  unsigned short* wout_t = (unsigned short*)(ws + 23068672);
  unsigned short* qkvb = (unsigned short*)(ws + 25165824);
  unsigned short* aout = (unsigned short*)(ws + 75497472);
  float* out = (float*)d_out;

  ln_bf16_kernel<<<BATCH * SEQ, 256, 0, stream>>>(x, gamma, beta, xn);
  transpose_cvt<<<dim3(QKV3 / 32, DIM / 32), dim3(32, 8), 0, stream>>>(
      w_qkv, wqkv_t, DIM, QKV3);
  transpose_cvt<<<dim3(DIM / 32, INNER / 32), dim3(32, 8), 0, stream>>>(
      w_out, wout_t, INNER, DIM);
  gemm_bt<false><<<(BATCH * SEQ / 128) * (QKV3 / 128), 256, 0, stream>>>(
      xn, wqkv_t, (void*)qkvb, BATCH * SEQ, QKV3, DIM);
  attn_kernel<<<BATCH * HEADS * (SEQ / 128), 256, 0, stream>>>(qkvb, bias, aout);
  gemm_bt<true><<<(BATCH * SEQ / 128) * (DIM / 128), 256, 0, stream>>>(
      aout, wout_t, d_out, BATCH * SEQ, DIM, INNER);
}